// Round 13
// baseline (314.971 us; speedup 1.0000x reference)
//
#include <hip/hip_runtime.h>

constexpr int B  = 8,  P = 50, N = 128, M = 128;
constexpr int EMB = 128, H = 8, D = 16;
constexpr int NE = 8;
constexpr int HD = H * D;        // 128
constexpr int E1 = EMB + 1;      // 129
constexpr int BP = B * P;        // 400
constexpr int T  = BP * N;       // 51200 tokens

// ---------------------------------------------------------------------------
// K0: We'[e][f] = sum_o We[e][f][o]*Wfinal[o]; b'[e] = be[e].Wfinal.
// ---------------------------------------------------------------------------
__global__ void prep_kernel(const float* __restrict__ We,
                            const float* __restrict__ be,
                            const float* __restrict__ Wf,
                            float* __restrict__ Wep, float* __restrict__ bpv,
                            float* __restrict__ importance) {
    const int e = blockIdx.x;
    const int f = threadIdx.x;

    float a = 0.f;
    const long base = ((long)e * HD + f) * E1;
    for (int o = 0; o < E1; ++o) a += We[base + o] * Wf[o];
    Wep[e * HD + f] = a;

    if (f == 0) {
        float b = 0.f;
        for (int o = 0; o < E1; ++o) b += be[(long)e * E1 + o] * Wf[o];
        bpv[e] = b;
    }
    if (e == 0 && f < NE) importance[f] = 0.f;
}

// ---------------------------------------------------------------------------
// K1: q/k/v projections. grid (400, 3), block 256. 128x128 tile, 8x8 acc,
// K-tile 16 (was 8): 9 barriers instead of 17, 1024 FMA per thread-tile.
// Ping-pong LDS double-buffer, reg-staged loads (r7-proven patterns).
// ---------------------------------------------------------------------------
__global__ __launch_bounds__(256) void proj_kernel(
    const float* __restrict__ nodes,  // [T][128]
    const float* __restrict__ routes, // [T][129]
    const float* __restrict__ Wq, const float* __restrict__ Wk,
    const float* __restrict__ Wv,
    float* __restrict__ qo, float* __restrict__ ko, float* __restrict__ vo) {
    const int mat = blockIdx.y;
    const float* __restrict__ X = (mat == 0) ? nodes : routes;
    const float* __restrict__ W = (mat == 0) ? Wq : (mat == 1 ? Wk : Wv);
    float* __restrict__ out     = (mat == 0) ? qo : (mat == 1 ? ko : vo);
    const int Kd = (mat == 0) ? EMB : E1;
    const int nit = (Kd + 15) >> 4;   // 8 (q) or 9 (k,v)

    const int row0 = blockIdx.x * 128;
    const int tid  = threadIdx.x;
    const int tr   = tid >> 4;        // 0..15
    const int tc   = tid & 15;        // 0..15

    __shared__ float XT[2][16][132];  // [buf][k][row], padded
    __shared__ float WS[2][16][132];  // [buf][k][col]

    float acc[8][8];
    #pragma unroll
    for (int i = 0; i < 8; ++i)
        #pragma unroll
        for (int j = 0; j < 8; ++j) acc[i][j] = 0.f;

    float xr[8];
    float4 wr0, wr1;
    const int xkx = tid & 15, xrr = tid >> 4;         // X: rows xrr + i*16
    const int wkx0 = tid >> 5, wkx1 = 8 + (tid >> 5); // W: two k-rows
    const int wc4  = (tid & 31) * 4;

    {   // prologue: fetch tile 0
        #pragma unroll
        for (int i = 0; i < 8; ++i) {
            int kg = xkx;
            xr[i] = (kg < Kd) ? X[(long)(row0 + xrr + i * 16) * Kd + kg] : 0.f;
        }
        wr0 = (wkx0 < Kd) ? *(const float4*)&W[(long)wkx0 * HD + wc4]
                          : make_float4(0.f, 0.f, 0.f, 0.f);
        wr1 = (wkx1 < Kd) ? *(const float4*)&W[(long)wkx1 * HD + wc4]
                          : make_float4(0.f, 0.f, 0.f, 0.f);
        #pragma unroll
        for (int i = 0; i < 8; ++i) XT[0][xkx][xrr + i * 16] = xr[i];
        *(float4*)&WS[0][wkx0][wc4] = wr0;
        *(float4*)&WS[0][wkx1][wc4] = wr1;
    }
    __syncthreads();

    for (int it = 0; it < nit; ++it) {
        const int buf = it & 1;
        if (it + 1 < nit) {           // prefetch next tile into registers
            const int kk = (it + 1) * 16;
            #pragma unroll
            for (int i = 0; i < 8; ++i) {
                int kg = kk + xkx;
                xr[i] = (kg < Kd) ? X[(long)(row0 + xrr + i * 16) * Kd + kg] : 0.f;
            }
            int kg0 = kk + wkx0, kg1 = kk + wkx1;
            wr0 = (kg0 < Kd) ? *(const float4*)&W[(long)kg0 * HD + wc4]
                             : make_float4(0.f, 0.f, 0.f, 0.f);
            wr1 = (kg1 < Kd) ? *(const float4*)&W[(long)kg1 * HD + wc4]
                             : make_float4(0.f, 0.f, 0.f, 0.f);
        }

        #pragma unroll
        for (int k = 0; k < 16; ++k) {
            float4 xa = *(const float4*)&XT[buf][k][tr * 4];
            float4 xb = *(const float4*)&XT[buf][k][64 + tr * 4];
            float4 wa = *(const float4*)&WS[buf][k][tc * 4];
            float4 wb = *(const float4*)&WS[buf][k][64 + tc * 4];
            float xv[8] = {xa.x, xa.y, xa.z, xa.w, xb.x, xb.y, xb.z, xb.w};
            float wvv[8] = {wa.x, wa.y, wa.z, wa.w, wb.x, wb.y, wb.z, wb.w};
            #pragma unroll
            for (int i = 0; i < 8; ++i)
                #pragma unroll
                for (int j = 0; j < 8; ++j) acc[i][j] += xv[i] * wvv[j];
        }

        if (it + 1 < nit) {           // stage into the other buffer
            const int nb = buf ^ 1;
            #pragma unroll
            for (int i = 0; i < 8; ++i) XT[nb][xkx][xrr + i * 16] = xr[i];
            *(float4*)&WS[nb][wkx0][wc4] = wr0;
            *(float4*)&WS[nb][wkx1][wc4] = wr1;
        }
        __syncthreads();
    }

    #pragma unroll
    for (int i = 0; i < 8; ++i) {
        int r = row0 + (i < 4 ? 0 : 64) + tr * 4 + (i & 3);
        float4 o0 = make_float4(acc[i][0], acc[i][1], acc[i][2], acc[i][3]);
        float4 o1 = make_float4(acc[i][4], acc[i][5], acc[i][6], acc[i][7]);
        *(float4*)&out[(long)r * HD + tc * 4]      = o0;
        *(float4*)&out[(long)r * HD + 64 + tc * 4] = o1;
    }
}

// ---------------------------------------------------------------------------
// K2: masked attention per (bp, head). grid (BP, 8), block 64 (1 wave).
// k staged in 8 KB LDS; v streams from global (wave-uniform broadcast).
// v prefetched into regs BEFORE the QK dot; dot split into two 8-FMA
// chains (shorter dep latency; ~1e-7 assoc. diff, below output bf16 grid).
// ---------------------------------------------------------------------------
__global__ __launch_bounds__(64) void attn_kernel(
    const float* __restrict__ qbuf,   // [T][128]
    const float* __restrict__ kbuf,   // [T][128]
    const float* __restrict__ vbuf,   // [T][128]
    const float* __restrict__ rmask,  // [BP*N][M]
    const float* __restrict__ ninf,   // [BP*N]
    float* __restrict__ xcat) {       // [T][128]
    const int bp  = blockIdx.x;
    const int h   = blockIdx.y;
    const int tid = threadIdx.x;

    __shared__ float kh[M][D];        // 8 KB (k only)

    // stage k: 512 float4s over 8 iterations (all 128 rows)
    #pragma unroll
    for (int i = 0; i < 8; ++i) {
        int e = tid + i * 64;
        int r = e >> 2, c4 = (e & 3) * 4;
        *(float4*)&kh[r][c4] = *(const float4*)&kbuf[((long)bp * M + r) * HD + h * D + c4];
    }
    __syncthreads();

    const long t0 = (long)bp * N + tid, t1 = t0 + 64;

    // q rows, 1/sqrt(D)=0.25 folded in
    float qr0[16], qr1[16];
    {
        const float4* q0 = (const float4*)&qbuf[t0 * HD + h * D];
        const float4* q1 = (const float4*)&qbuf[t1 * HD + h * D];
        #pragma unroll
        for (int i = 0; i < 4; ++i) {
            float4 a = q0[i], b = q1[i];
            qr0[i*4+0] = a.x*0.25f; qr0[i*4+1] = a.y*0.25f;
            qr0[i*4+2] = a.z*0.25f; qr0[i*4+3] = a.w*0.25f;
            qr1[i*4+0] = b.x*0.25f; qr1[i*4+1] = b.y*0.25f;
            qr1[i*4+2] = b.z*0.25f; qr1[i*4+3] = b.w*0.25f;
        }
    }

    const float* __restrict__ vbase = vbuf + ((long)bp * M) * HD + h * D;
    const float4* rm0 = (const float4*)&rmask[t0 * M];
    const float4* rm1 = (const float4*)&rmask[t1 * M];

    float sum0 = 0.f, sum1 = 0.f;
    float o0[16], o1[16];
    #pragma unroll
    for (int d = 0; d < 16; ++d) { o0[d] = 0.f; o1[d] = 0.f; }

    for (int mb = 0; mb < 32; ++mb) {          // NOT force-unrolled (VGPR!)
        float4 r0 = rm0[mb], r1 = rm1[mb];
        float r0v[4] = {r0.x, r0.y, r0.z, r0.w};
        float r1v[4] = {r1.x, r1.y, r1.z, r1.w};
        #pragma unroll
        for (int j = 0; j < 4; ++j) {
            const int m = mb * 4 + j;
            const float4* k4 = (const float4*)&kh[m][0];
            const float4* vg = (const float4*)&vbase[(long)m * HD];
            // prefetch v early: global latency hides under the dot below
            float4 vq0 = vg[0], vq1 = vg[1], vq2 = vg[2], vq3 = vg[3];

            float4 kq0 = k4[0], kq1 = k4[1], kq2 = k4[2], kq3 = k4[3];
            float s0a = qr0[0]*kq0.x + qr0[1]*kq0.y + qr0[2]*kq0.z + qr0[3]*kq0.w
                      + qr0[4]*kq1.x + qr0[5]*kq1.y + qr0[6]*kq1.z + qr0[7]*kq1.w;
            float s0b = qr0[8]*kq2.x + qr0[9]*kq2.y + qr0[10]*kq2.z + qr0[11]*kq2.w
                      + qr0[12]*kq3.x + qr0[13]*kq3.y + qr0[14]*kq3.z + qr0[15]*kq3.w;
            float s1a = qr1[0]*kq0.x + qr1[1]*kq0.y + qr1[2]*kq0.z + qr1[3]*kq0.w
                      + qr1[4]*kq1.x + qr1[5]*kq1.y + qr1[6]*kq1.z + qr1[7]*kq1.w;
            float s1b = qr1[8]*kq2.x + qr1[9]*kq2.y + qr1[10]*kq2.z + qr1[11]*kq2.w
                      + qr1[12]*kq3.x + qr1[13]*kq3.y + qr1[14]*kq3.z + qr1[15]*kq3.w;

            float e0 = __expf(s0a + s0b + r0v[j]);
            float e1 = __expf(s1a + s1b + r1v[j]);
            sum0 += e0; sum1 += e1;

            o0[0] += e0*vq0.x; o0[1] += e0*vq0.y; o0[2] += e0*vq0.z; o0[3] += e0*vq0.w;
            o0[4] += e0*vq1.x; o0[5] += e0*vq1.y; o0[6] += e0*vq1.z; o0[7] += e0*vq1.w;
            o0[8] += e0*vq2.x; o0[9] += e0*vq2.y; o0[10] += e0*vq2.z; o0[11] += e0*vq2.w;
            o0[12] += e0*vq3.x; o0[13] += e0*vq3.y; o0[14] += e0*vq3.z; o0[15] += e0*vq3.w;
            o1[0] += e1*vq0.x; o1[1] += e1*vq0.y; o1[2] += e1*vq0.z; o1[3] += e1*vq0.w;
            o1[4] += e1*vq1.x; o1[5] += e1*vq1.y; o1[6] += e1*vq1.z; o1[7] += e1*vq1.w;
            o1[8] += e1*vq2.x; o1[9] += e1*vq2.y; o1[10] += e1*vq2.z; o1[11] += e1*vq2.w;
            o1[12] += e1*vq3.x; o1[13] += e1*vq3.y; o1[14] += e1*vq3.z; o1[15] += e1*vq3.w;
        }
    }

    const float inv0 = ((ninf[t0] == 0.f) ? 1.f : 0.f) / sum0;
    const float inv1 = ((ninf[t1] == 0.f) ? 1.f : 0.f) / sum1;
    #pragma unroll
    for (int q4 = 0; q4 < 4; ++q4) {
        float4 w0 = make_float4(o0[q4*4+0]*inv0, o0[q4*4+1]*inv0,
                                o0[q4*4+2]*inv0, o0[q4*4+3]*inv0);
        float4 w1 = make_float4(o1[q4*4+0]*inv1, o1[q4*4+1]*inv1,
                                o1[q4*4+2]*inv1, o1[q4*4+3]*inv1);
        *(float4*)&xcat[t0 * HD + h * D + q4 * 4] = w0;
        *(float4*)&xcat[t1 * HD + h * D + q4 * 4] = w1;
    }
}

// ---------------------------------------------------------------------------
// K3: MoE gating (top-2) + collapsed expert scoring + final softmax.
// grid BP, block 128 (thread = token n). (r5/r7-proven version)
// ---------------------------------------------------------------------------
__global__ __launch_bounds__(128) void moe_final_kernel(
    const float* __restrict__ xcat, const float* __restrict__ Wg,
    const float* __restrict__ ninf, const float* __restrict__ Wep,
    const float* __restrict__ bpv, float* __restrict__ importance,
    float* __restrict__ out) {
    __shared__ float WgS[EMB][NE];   // 4 KB
    __shared__ float WeS[NE][132];   // padded
    __shared__ float red[N];
    __shared__ float impS[NE];

    const int bp = blockIdx.x;
    const int n  = threadIdx.x;

    #pragma unroll
    for (int i = 0; i < 2; ++i) {
        int e = n + i * 128;
        int r = e >> 1, c4 = (e & 1) * 4;
        *(float4*)&WgS[r][c4] = *(const float4*)&Wg[(long)r * NE + c4];
    }
    #pragma unroll
    for (int i = 0; i < 2; ++i) {
        int idx = n + i * 128;
        int r = idx >> 5, c = (idx & 31) * 4;
        *(float4*)&WeS[r][c] = *(const float4*)&Wep[(long)r * HD + c];
    }
    if (n < NE) impS[n] = 0.f;
    __syncthreads();

    const long t = (long)bp * N + n;
    const float4* row4 = (const float4*)&xcat[t * HD];

    float gl[NE];
    #pragma unroll
    for (int e = 0; e < NE; ++e) gl[e] = 0.f;
    for (int fb = 0; fb < 32; ++fb) {
        float4 xv = row4[fb];
        float x4[4] = {xv.x, xv.y, xv.z, xv.w};
        #pragma unroll
        for (int j = 0; j < 4; ++j)
            #pragma unroll
            for (int e = 0; e < NE; ++e) gl[e] += x4[j] * WgS[fb * 4 + j][e];
    }

    int e0 = 0; float v0 = gl[0];
    #pragma unroll
    for (int e = 1; e < NE; ++e) if (gl[e] > v0) { v0 = gl[e]; e0 = e; }
    int e1 = -1; float v1 = -3.4e38f;
    #pragma unroll
    for (int e = 0; e < NE; ++e) if (e != e0 && gl[e] > v1) { v1 = gl[e]; e1 = e; }
    float ex = __expf(v1 - v0);
    float g0 = 1.f / (1.f + ex);
    float g1 = ex / (1.f + ex);

    atomicAdd(&impS[e0], g0);
    atomicAdd(&impS[e1], g1);

    float s = g0 * bpv[e0] + g1 * bpv[e1];
    for (int fb = 0; fb < 32; ++fb) {
        float4 xv = row4[fb];
        float x4[4] = {xv.x, xv.y, xv.z, xv.w};
        #pragma unroll
        for (int j = 0; j < 4; ++j) {
            int f = fb * 4 + j;
            s += x4[j] * (g0 * WeS[e0][f] + g1 * WeS[e1][f]);
        }
    }
    s = 10.f * tanhf(s) + ninf[t];

    red[n] = s;
    __syncthreads();
    for (int off = 64; off > 0; off >>= 1) {
        if (n < off) red[n] = fmaxf(red[n], red[n + off]);
        __syncthreads();
    }
    float mx = red[0];
    __syncthreads();
    float e = __expf(s - mx);
    red[n] = e;
    __syncthreads();
    for (int off = 64; off > 0; off >>= 1) {
        if (n < off) red[n] += red[n + off];
        __syncthreads();
    }
    float sum = red[0];

    out[t] = e / sum;

    if (n < NE) atomicAdd(&importance[n], impS[n]);
}

// ---------------------------------------------------------------------------
// K4: moe_loss from importance (f32 at out[T]).
// ---------------------------------------------------------------------------
__global__ void loss_kernel(const float* __restrict__ importance,
                            float* __restrict__ out) {
    if (threadIdx.x == 0) {
        float mean = 0.f;
        #pragma unroll
        for (int e = 0; e < NE; ++e) mean += importance[e];
        mean *= (1.f / NE);
        float var = 0.f;
        #pragma unroll
        for (int e = 0; e < NE; ++e) {
            float d = importance[e] - mean;
            var += d * d;
        }
        var *= (1.f / NE);
        out[T] = var / (mean * mean + 1e-10f);
    }
}

// ---------------------------------------------------------------------------
extern "C" void kernel_launch(void* const* d_in, const int* in_sizes, int n_in,
                              void* d_out, int out_size, void* d_ws, size_t ws_size,
                              hipStream_t stream) {
    const float* nodes  = (const float*)d_in[0];
    const float* routes = (const float*)d_in[1];
    const float* ninf   = (const float*)d_in[2];
    const float* rmask  = (const float*)d_in[3];
    const float* Wq     = (const float*)d_in[4];
    const float* Wk     = (const float*)d_in[5];
    const float* Wv     = (const float*)d_in[6];
    const float* Wg     = (const float*)d_in[7];
    const float* We     = (const float*)d_in[8];
    const float* be     = (const float*)d_in[9];
    const float* Wfin   = (const float*)d_in[10];

    float* ws = (float*)d_ws;
    float* Wep        = ws + 16;
    float* bpv        = ws + 1040;
    float* importance = ws + 1048;
    float* qbuf       = ws + 4096;
    float* kbuf       = qbuf + (long)T * HD;
    float* vbuf       = kbuf + (long)T * HD;
    float* xcat       = vbuf + (long)T * HD;

    float* out = (float*)d_out;

    prep_kernel<<<NE, 128, 0, stream>>>(We, be, Wfin, Wep, bpv, importance);
    proj_kernel<<<dim3(400, 3), 256, 0, stream>>>(nodes, routes, Wq, Wk, Wv,
                                                  qbuf, kbuf, vbuf);
    attn_kernel<<<dim3(BP, H), 64, 0, stream>>>(qbuf, kbuf, vbuf,
                                                rmask, ninf, xcat);
    moe_final_kernel<<<BP, 128, 0, stream>>>(xcat, Wg, ninf, Wep, bpv,
                                             importance, out);
    loss_kernel<<<1, 64, 0, stream>>>(importance, out);
}

// Round 14
// 302.793 us; speedup vs baseline: 1.0402x; 1.0402x over previous
//
#include <hip/hip_runtime.h>

constexpr int B  = 8,  P = 50, N = 128, M = 128;
constexpr int EMB = 128, H = 8, D = 16;
constexpr int NE = 8;
constexpr int HD = H * D;        // 128
constexpr int E1 = EMB + 1;      // 129
constexpr int BP = B * P;        // 400
constexpr int T  = BP * N;       // 51200 tokens

// ---------------------------------------------------------------------------
// K0: We'[e][f] = sum_o We[e][f][o]*Wfinal[o]; b'[e] = be[e].Wfinal.
// ---------------------------------------------------------------------------
__global__ void prep_kernel(const float* __restrict__ We,
                            const float* __restrict__ be,
                            const float* __restrict__ Wf,
                            float* __restrict__ Wep, float* __restrict__ bpv,
                            float* __restrict__ importance) {
    const int e = blockIdx.x;
    const int f = threadIdx.x;

    float a = 0.f;
    const long base = ((long)e * HD + f) * E1;
    for (int o = 0; o < E1; ++o) a += We[base + o] * Wf[o];
    Wep[e * HD + f] = a;

    if (f == 0) {
        float b = 0.f;
        for (int o = 0; o < E1; ++o) b += be[(long)e * E1 + o] * Wf[o];
        bpv[e] = b;
    }
    if (e == 0 && f < NE) importance[f] = 0.f;
}

// ---------------------------------------------------------------------------
// K1: q/k/v projections (r12-proven, BK=8). grid (400, 3), block 256.
// 128x128 tile, 8x8 acc, ping-pong LDS, one barrier per tile.
// ---------------------------------------------------------------------------
__global__ __launch_bounds__(256) void proj_kernel(
    const float* __restrict__ nodes,  // [T][128]
    const float* __restrict__ routes, // [T][129]
    const float* __restrict__ Wq, const float* __restrict__ Wk,
    const float* __restrict__ Wv,
    float* __restrict__ qo, float* __restrict__ ko, float* __restrict__ vo) {
    const int mat = blockIdx.y;
    const float* __restrict__ X = (mat == 0) ? nodes : routes;
    const float* __restrict__ W = (mat == 0) ? Wq : (mat == 1 ? Wk : Wv);
    float* __restrict__ out     = (mat == 0) ? qo : (mat == 1 ? ko : vo);
    const int Kd = (mat == 0) ? EMB : E1;
    const int nit = (Kd + 7) >> 3;

    const int row0 = blockIdx.x * 128;
    const int tid  = threadIdx.x;
    const int tr   = tid >> 4;        // 0..15
    const int tc   = tid & 15;        // 0..15

    __shared__ float XT[2][8][132];   // [buf][k][row], padded
    __shared__ float WS[2][8][132];   // [buf][k][col]

    float acc[8][8];
    #pragma unroll
    for (int i = 0; i < 8; ++i)
        #pragma unroll
        for (int j = 0; j < 8; ++j) acc[i][j] = 0.f;

    float xr[4];
    float4 wr;
    const int xkx = tid & 7, xrr = tid >> 3;          // +i*32 rows
    const int wkx = tid >> 5, wc4 = (tid & 31) * 4;

    {   // prologue: fetch tile 0
        #pragma unroll
        for (int i = 0; i < 4; ++i) {
            int kg = xkx;
            xr[i] = (kg < Kd) ? X[(long)(row0 + xrr + i * 32) * Kd + kg] : 0.f;
        }
        wr = (wkx < Kd) ? *(const float4*)&W[(long)wkx * HD + wc4]
                        : make_float4(0.f, 0.f, 0.f, 0.f);
        #pragma unroll
        for (int i = 0; i < 4; ++i) XT[0][xkx][xrr + i * 32] = xr[i];
        *(float4*)&WS[0][wkx][wc4] = wr;
    }
    __syncthreads();

    for (int it = 0; it < nit; ++it) {
        const int buf = it & 1;
        if (it + 1 < nit) {
            const int kk = (it + 1) * 8;
            #pragma unroll
            for (int i = 0; i < 4; ++i) {
                int kg = kk + xkx;
                xr[i] = (kg < Kd) ? X[(long)(row0 + xrr + i * 32) * Kd + kg] : 0.f;
            }
            int kg = kk + wkx;
            wr = (kg < Kd) ? *(const float4*)&W[(long)kg * HD + wc4]
                           : make_float4(0.f, 0.f, 0.f, 0.f);
        }

        #pragma unroll
        for (int k = 0; k < 8; ++k) {
            float4 xa = *(const float4*)&XT[buf][k][tr * 4];
            float4 xb = *(const float4*)&XT[buf][k][64 + tr * 4];
            float4 wa = *(const float4*)&WS[buf][k][tc * 4];
            float4 wb = *(const float4*)&WS[buf][k][64 + tc * 4];
            float xv[8] = {xa.x, xa.y, xa.z, xa.w, xb.x, xb.y, xb.z, xb.w};
            float wvv[8] = {wa.x, wa.y, wa.z, wa.w, wb.x, wb.y, wb.z, wb.w};
            #pragma unroll
            for (int i = 0; i < 8; ++i)
                #pragma unroll
                for (int j = 0; j < 8; ++j) acc[i][j] += xv[i] * wvv[j];
        }

        if (it + 1 < nit) {
            const int nb = buf ^ 1;
            #pragma unroll
            for (int i = 0; i < 4; ++i) XT[nb][xkx][xrr + i * 32] = xr[i];
            *(float4*)&WS[nb][wkx][wc4] = wr;
        }
        __syncthreads();
    }

    #pragma unroll
    for (int i = 0; i < 8; ++i) {
        int r = row0 + (i < 4 ? 0 : 64) + tr * 4 + (i & 3);
        float4 o0 = make_float4(acc[i][0], acc[i][1], acc[i][2], acc[i][3]);
        float4 o1 = make_float4(acc[i][4], acc[i][5], acc[i][6], acc[i][7]);
        *(float4*)&out[(long)r * HD + tc * 4]      = o0;
        *(float4*)&out[(long)r * HD + 64 + tc * 4] = o1;
    }
}

// ---------------------------------------------------------------------------
// K2: masked attention. grid (BP, 8, 2), block 64 (1 wave).
// blockIdx.z selects query-row half; each thread owns ONE query row
// (n = z*64 + tid). k staged in 8 KB LDS (all 128 m rows); v streams from
// global (wave-uniform broadcast). Per-token serial order identical to r12
// -> bit-identical. Grid 6400 blocks: 25 wanted/CU vs LDS cap 20 (was 12.5).
// ---------------------------------------------------------------------------
__global__ __launch_bounds__(64) void attn_kernel(
    const float* __restrict__ qbuf,   // [T][128]
    const float* __restrict__ kbuf,   // [T][128]
    const float* __restrict__ vbuf,   // [T][128]
    const float* __restrict__ rmask,  // [BP*N][M]
    const float* __restrict__ ninf,   // [BP*N]
    float* __restrict__ xcat) {       // [T][128]
    const int bp  = blockIdx.x;
    const int h   = blockIdx.y;
    const int tid = threadIdx.x;

    __shared__ float kh[M][D];        // 8 KB (k only)

    // stage k: 512 float4s over 8 iterations (all 128 m rows)
    #pragma unroll
    for (int i = 0; i < 8; ++i) {
        int e = tid + i * 64;
        int r = e >> 2, c4 = (e & 3) * 4;
        *(float4*)&kh[r][c4] = *(const float4*)&kbuf[((long)bp * M + r) * HD + h * D + c4];
    }
    __syncthreads();

    const long t0 = (long)bp * N + blockIdx.z * 64 + tid;

    // q row, 1/sqrt(D)=0.25 folded in
    float qr0[16];
    {
        const float4* q0 = (const float4*)&qbuf[t0 * HD + h * D];
        #pragma unroll
        for (int i = 0; i < 4; ++i) {
            float4 a = q0[i];
            qr0[i*4+0] = a.x*0.25f; qr0[i*4+1] = a.y*0.25f;
            qr0[i*4+2] = a.z*0.25f; qr0[i*4+3] = a.w*0.25f;
        }
    }

    const float* __restrict__ vbase = vbuf + ((long)bp * M) * HD + h * D;
    const float4* rm0 = (const float4*)&rmask[t0 * M];

    float sum0 = 0.f;
    float o0[16];
    #pragma unroll
    for (int d = 0; d < 16; ++d) o0[d] = 0.f;

    for (int mb = 0; mb < 32; ++mb) {          // NOT force-unrolled (VGPR!)
        float4 r0 = rm0[mb];
        float r0v[4] = {r0.x, r0.y, r0.z, r0.w};
        #pragma unroll
        for (int j = 0; j < 4; ++j) {
            const int m = mb * 4 + j;
            const float4* k4 = (const float4*)&kh[m][0];
            const float4* v4 = (const float4*)&vbase[(long)m * HD];  // global, wave-uniform
            float s0 = 0.f;
            #pragma unroll
            for (int q4 = 0; q4 < 4; ++q4) {
                float4 kq = k4[q4];
                s0 += qr0[q4*4+0]*kq.x + qr0[q4*4+1]*kq.y
                    + qr0[q4*4+2]*kq.z + qr0[q4*4+3]*kq.w;
            }
            float e0 = __expf(s0 + r0v[j]);
            sum0 += e0;
            #pragma unroll
            for (int q4 = 0; q4 < 4; ++q4) {
                float4 vq = v4[q4];
                o0[q4*4+0] += e0*vq.x; o0[q4*4+1] += e0*vq.y;
                o0[q4*4+2] += e0*vq.z; o0[q4*4+3] += e0*vq.w;
            }
        }
    }

    const float inv0 = ((ninf[t0] == 0.f) ? 1.f : 0.f) / sum0;
    #pragma unroll
    for (int q4 = 0; q4 < 4; ++q4) {
        float4 w0 = make_float4(o0[q4*4+0]*inv0, o0[q4*4+1]*inv0,
                                o0[q4*4+2]*inv0, o0[q4*4+3]*inv0);
        *(float4*)&xcat[t0 * HD + h * D + q4 * 4] = w0;
    }
}

// ---------------------------------------------------------------------------
// K3: MoE gating (top-2) + collapsed expert scoring + final softmax.
// grid BP, block 128 (thread = token n). (r5/r7/r12-proven version)
// ---------------------------------------------------------------------------
__global__ __launch_bounds__(128) void moe_final_kernel(
    const float* __restrict__ xcat, const float* __restrict__ Wg,
    const float* __restrict__ ninf, const float* __restrict__ Wep,
    const float* __restrict__ bpv, float* __restrict__ importance,
    float* __restrict__ out) {
    __shared__ float WgS[EMB][NE];   // 4 KB
    __shared__ float WeS[NE][132];   // padded
    __shared__ float red[N];
    __shared__ float impS[NE];

    const int bp = blockIdx.x;
    const int n  = threadIdx.x;

    #pragma unroll
    for (int i = 0; i < 2; ++i) {
        int e = n + i * 128;
        int r = e >> 1, c4 = (e & 1) * 4;
        *(float4*)&WgS[r][c4] = *(const float4*)&Wg[(long)r * NE + c4];
    }
    #pragma unroll
    for (int i = 0; i < 2; ++i) {
        int idx = n + i * 128;
        int r = idx >> 5, c = (idx & 31) * 4;
        *(float4*)&WeS[r][c] = *(const float4*)&Wep[(long)r * HD + c];
    }
    if (n < NE) impS[n] = 0.f;
    __syncthreads();

    const long t = (long)bp * N + n;
    const float4* row4 = (const float4*)&xcat[t * HD];

    float gl[NE];
    #pragma unroll
    for (int e = 0; e < NE; ++e) gl[e] = 0.f;
    for (int fb = 0; fb < 32; ++fb) {
        float4 xv = row4[fb];
        float x4[4] = {xv.x, xv.y, xv.z, xv.w};
        #pragma unroll
        for (int j = 0; j < 4; ++j)
            #pragma unroll
            for (int e = 0; e < NE; ++e) gl[e] += x4[j] * WgS[fb * 4 + j][e];
    }

    int e0 = 0; float v0 = gl[0];
    #pragma unroll
    for (int e = 1; e < NE; ++e) if (gl[e] > v0) { v0 = gl[e]; e0 = e; }
    int e1 = -1; float v1 = -3.4e38f;
    #pragma unroll
    for (int e = 0; e < NE; ++e) if (e != e0 && gl[e] > v1) { v1 = gl[e]; e1 = e; }
    float ex = __expf(v1 - v0);
    float g0 = 1.f / (1.f + ex);
    float g1 = ex / (1.f + ex);

    atomicAdd(&impS[e0], g0);
    atomicAdd(&impS[e1], g1);

    float s = g0 * bpv[e0] + g1 * bpv[e1];
    for (int fb = 0; fb < 32; ++fb) {
        float4 xv = row4[fb];
        float x4[4] = {xv.x, xv.y, xv.z, xv.w};
        #pragma unroll
        for (int j = 0; j < 4; ++j) {
            int f = fb * 4 + j;
            s += x4[j] * (g0 * WeS[e0][f] + g1 * WeS[e1][f]);
        }
    }
    s = 10.f * tanhf(s) + ninf[t];

    red[n] = s;
    __syncthreads();
    for (int off = 64; off > 0; off >>= 1) {
        if (n < off) red[n] = fmaxf(red[n], red[n + off]);
        __syncthreads();
    }
    float mx = red[0];
    __syncthreads();
    float e = __expf(s - mx);
    red[n] = e;
    __syncthreads();
    for (int off = 64; off > 0; off >>= 1) {
        if (n < off) red[n] += red[n + off];
        __syncthreads();
    }
    float sum = red[0];

    out[t] = e / sum;

    if (n < NE) atomicAdd(&importance[n], impS[n]);
}

// ---------------------------------------------------------------------------
// K4: moe_loss from importance (f32 at out[T]).
// ---------------------------------------------------------------------------
__global__ void loss_kernel(const float* __restrict__ importance,
                            float* __restrict__ out) {
    if (threadIdx.x == 0) {
        float mean = 0.f;
        #pragma unroll
        for (int e = 0; e < NE; ++e) mean += importance[e];
        mean *= (1.f / NE);
        float var = 0.f;
        #pragma unroll
        for (int e = 0; e < NE; ++e) {
            float d = importance[e] - mean;
            var += d * d;
        }
        var *= (1.f / NE);
        out[T] = var / (mean * mean + 1e-10f);
    }
}

// ---------------------------------------------------------------------------
extern "C" void kernel_launch(void* const* d_in, const int* in_sizes, int n_in,
                              void* d_out, int out_size, void* d_ws, size_t ws_size,
                              hipStream_t stream) {
    const float* nodes  = (const float*)d_in[0];
    const float* routes = (const float*)d_in[1];
    const float* ninf   = (const float*)d_in[2];
    const float* rmask  = (const float*)d_in[3];
    const float* Wq     = (const float*)d_in[4];
    const float* Wk     = (const float*)d_in[5];
    const float* Wv     = (const float*)d_in[6];
    const float* Wg     = (const float*)d_in[7];
    const float* We     = (const float*)d_in[8];
    const float* be     = (const float*)d_in[9];
    const float* Wfin   = (const float*)d_in[10];

    float* ws = (float*)d_ws;
    float* Wep        = ws + 16;
    float* bpv        = ws + 1040;
    float* importance = ws + 1048;
    float* qbuf       = ws + 4096;
    float* kbuf       = qbuf + (long)T * HD;
    float* vbuf       = kbuf + (long)T * HD;
    float* xcat       = vbuf + (long)T * HD;

    float* out = (float*)d_out;

    prep_kernel<<<NE, 128, 0, stream>>>(We, be, Wfin, Wep, bpv, importance);
    proj_kernel<<<dim3(400, 3), 256, 0, stream>>>(nodes, routes, Wq, Wk, Wv,
                                                  qbuf, kbuf, vbuf);
    attn_kernel<<<dim3(BP, H, 2), 64, 0, stream>>>(qbuf, kbuf, vbuf,
                                                   rmask, ninf, xcat);
    moe_final_kernel<<<BP, 128, 0, stream>>>(xcat, Wg, ninf, Wep, bpv,
                                             importance, out);
    loss_kernel<<<1, 64, 0, stream>>>(importance, out);
}